// Round 1
// baseline (432.872 us; speedup 1.0000x reference)
//
#include <hip/hip_runtime.h>

// Problem constants (fixed by the reference)
#define NN 200000   // nodes
#define CC 256      // channels
#define NH 4        // heads
#define HD 64       // head dim
#define NG 512      // graphs/segments
#define BM 64       // node rows per block (200000 = 3125 * 64 exactly)

typedef __attribute__((ext_vector_type(8))) __bf16 bf16x8;
typedef __attribute__((ext_vector_type(4))) float f32x4;

__device__ __forceinline__ unsigned short f2bf(float f) {
  union { float f; unsigned u; } v; v.f = f;
  unsigned u = v.u;
  u += 0x7fffu + ((u >> 16) & 1u);   // RNE
  return (unsigned short)(u >> 16);
}
__device__ __forceinline__ float bflo(unsigned u){ union{unsigned u; float f;} x; x.u = u << 16; return x.f; }
__device__ __forceinline__ float bfhi(unsigned u){ union{unsigned u; float f;} x; x.u = u & 0xffff0000u; return x.f; }

// ---------------------------------------------------------------------------
// K0: build bf16 transposed weights.  Wqkv_t[c][k] (c in 0..767), Wo_t[c][k].
// ---------------------------------------------------------------------------
__global__ __launch_bounds__(256) void prep_kernel(
    const float* __restrict__ Wq, const float* __restrict__ Wk,
    const float* __restrict__ Wv, const float* __restrict__ Wo,
    unsigned short* __restrict__ Wqkv_t, unsigned short* __restrict__ Wo_t) {
  int idx = blockIdx.x * 256 + threadIdx.x;
  const int total1 = 768 * 256;
  if (idx < total1) {
    int c = idx >> 8, k = idx & 255;
    float w;
    if (c < 256)      w = Wq[k * 256 + c];
    else if (c < 512) w = Wk[k * 256 + (c - 256)];
    else              w = Wv[k * 256 + (c - 512)];
    Wqkv_t[idx] = f2bf(w);
  } else {
    int j = idx - total1;   // < 256*256 (grid sized exactly)
    int c = j >> 8, k = j & 255;
    Wo_t[j] = f2bf(Wo[k * 256 + c]);
  }
}

// ---------------------------------------------------------------------------
// K1: segment boundaries from sorted batch.  seg_start[g] = first i with batch[i] >= g.
// ---------------------------------------------------------------------------
__global__ __launch_bounds__(256) void seg_bounds_kernel(
    const int* __restrict__ batch, int* __restrict__ seg_start, int n) {
  int i = blockIdx.x * 256 + threadIdx.x;
  if (i >= n) return;
  int a = batch[i];
  int b = (i + 1 < n) ? batch[i + 1] : NG;
  for (int g = a + 1; g <= b; ++g) seg_start[g] = i + 1;
  if (i == 0) for (int g = 0; g <= a; ++g) seg_start[g] = 0;
}

// ---------------------------------------------------------------------------
// K2: fused QKV GEMM + per-node scores.
//   Block = 64 node rows. x staged to LDS bf16 (padded).  12 chunks of 64 W cols.
//   q,k chunks -> LDS QK buffer (never to HBM); v chunks -> global bf16 (via LDS
//   coalesce).  Epilogue: scores[n][h*4+g] = q_h . k_g / 8.
// LDS: A 33792 + B 33792 + QK 67584 + Vst 9216 = 144384 B -> 1 block/CU.
// ---------------------------------------------------------------------------
__global__ __launch_bounds__(256) void qkv_scores_kernel(
    const float* __restrict__ x, const unsigned short* __restrict__ Wqkv_t,
    const float* __restrict__ bq, const float* __restrict__ bk,
    const float* __restrict__ bv,
    unsigned short* __restrict__ v_out,   // [NN][256] bf16
    float* __restrict__ scores) {         // [NN][16]
  __shared__ unsigned short Atile[BM][CC + 8];
  __shared__ unsigned short Btile[64][CC + 8];
  __shared__ unsigned short QK[BM][512 + 16];
  __shared__ unsigned short Vst[BM][72];

  const int t = threadIdx.x;
  const int lane = t & 63;
  const int wave = t >> 6;
  const int lr = lane & 15;
  const int hi = lane >> 4;
  const int r0 = blockIdx.x * BM;

  // stage x tile: 64 rows x 256 fp32 -> bf16 LDS (coalesced float4)
#pragma unroll
  for (int u = 0; u < 16; ++u) {
    int unit = t + u * 256;
    int row = unit >> 6, c4 = unit & 63;
    const float4 v = *reinterpret_cast<const float4*>(x + (size_t)(r0 + row) * CC + c4 * 4);
    uint2 pk;
    pk.x = (unsigned)f2bf(v.x) | ((unsigned)f2bf(v.y) << 16);
    pk.y = (unsigned)f2bf(v.z) | ((unsigned)f2bf(v.w) << 16);
    *reinterpret_cast<uint2*>(&Atile[row][c4 * 4]) = pk;
  }

  for (int c = 0; c < 12; ++c) {
    __syncthreads();   // prev chunk's B reads / Vst copy done
    // stage B chunk: W^T rows c*64..+63, each 256 bf16 (coalesced 16B units)
#pragma unroll
    for (int u = 0; u < 8; ++u) {
      int unit = t + u * 256;
      int row = unit >> 5, s8 = unit & 31;
      const uint4 w = *reinterpret_cast<const uint4*>(Wqkv_t + (size_t)(c * 64 + row) * 256 + s8 * 8);
      *reinterpret_cast<uint4*>(&Btile[row][s8 * 8]) = w;
    }
    __syncthreads();

    f32x4 acc[4];
#pragma unroll
    for (int m = 0; m < 4; ++m) acc[m] = (f32x4){0.f, 0.f, 0.f, 0.f};

#pragma unroll
    for (int ks = 0; ks < 8; ++ks) {
      bf16x8 bfrag = *reinterpret_cast<const bf16x8*>(&Btile[wave * 16 + lr][ks * 32 + hi * 8]);
#pragma unroll
      for (int m = 0; m < 4; ++m) {
        bf16x8 afrag = *reinterpret_cast<const bf16x8*>(&Atile[m * 16 + lr][ks * 32 + hi * 8]);
        acc[m] = __builtin_amdgcn_mfma_f32_16x16x32_bf16(afrag, bfrag, acc[m], 0, 0, 0);
      }
    }

    if (c < 8) {           // q,k -> LDS QK (+bias)
      int colL = c * 64 + wave * 16 + lr;    // 0..511
      float bias = (colL < 256) ? bq[colL] : bk[colL - 256];
#pragma unroll
      for (int m = 0; m < 4; ++m)
#pragma unroll
        for (int r = 0; r < 4; ++r) {
          int row = m * 16 + hi * 4 + r;
          QK[row][colL] = f2bf(acc[m][r] + bias);
        }
    } else {               // v -> LDS stage -> coalesced global bf16
      int cv = c - 8;
      int colv = cv * 64 + wave * 16 + lr;
      float bias = bv[colv];
#pragma unroll
      for (int m = 0; m < 4; ++m)
#pragma unroll
        for (int r = 0; r < 4; ++r) {
          int row = m * 16 + hi * 4 + r;
          Vst[row][wave * 16 + lr] = f2bf(acc[m][r] + bias);
        }
      __syncthreads();
#pragma unroll
      for (int u = 0; u < 2; ++u) {
        int unit = t + u * 256;
        int row = unit >> 3, s8 = unit & 7;
        uint4 w = *reinterpret_cast<const uint4*>(&Vst[row][s8 * 8]);
        *reinterpret_cast<uint4*>(v_out + (size_t)(r0 + row) * CC + cv * 64 + s8 * 8) = w;
      }
    }
  }

  __syncthreads();
  // scores: 64 nodes x 16 (h,g) pairs; dot of 64 from QK LDS, fp32 accumulate
#pragma unroll
  for (int it = 0; it < 4; ++it) {
    int node = (t >> 4) + it * 16;
    int col = t & 15;
    int h = col >> 2, g = col & 3;
    float s = 0.f;
#pragma unroll
    for (int d0 = 0; d0 < 64; d0 += 8) {
      uint4 qv = *reinterpret_cast<const uint4*>(&QK[node][h * 64 + d0]);
      uint4 kv = *reinterpret_cast<const uint4*>(&QK[node][256 + g * 64 + d0]);
      s += bflo(qv.x) * bflo(kv.x) + bfhi(qv.x) * bfhi(kv.x);
      s += bflo(qv.y) * bflo(kv.y) + bfhi(qv.y) * bfhi(kv.y);
      s += bflo(qv.z) * bflo(kv.z) + bfhi(qv.z) * bfhi(kv.z);
      s += bflo(qv.w) * bflo(kv.w) + bfhi(qv.w) * bfhi(kv.w);
    }
    scores[(size_t)(r0 + node) * 16 + col] = s * 0.125f;
  }
}

// ---------------------------------------------------------------------------
// K3: per-segment max & exp-sum over the 16 score columns (block per segment).
// ---------------------------------------------------------------------------
__global__ __launch_bounds__(256) void seg_softmax_kernel(
    const float* __restrict__ scores, const int* __restrict__ seg_start,
    float* __restrict__ seg_max, float* __restrict__ seg_sum) {
  __shared__ float red[256];
  int g = blockIdx.x;
  int s = seg_start[g], e = seg_start[g + 1];
  int t = threadIdx.x;
  int col = t & 15, sub = t >> 4;

  float m = -INFINITY;
  for (int i = s + sub; i < e; i += 16)
    m = fmaxf(m, scores[(size_t)i * 16 + col]);
  red[t] = m;
  __syncthreads();
  for (int step = 8; step >= 1; step >>= 1) {
    if (sub < step) red[t] = fmaxf(red[t], red[t + step * 16]);
    __syncthreads();
  }
  if (t < 16) seg_max[g * 16 + t] = red[t];
  float mcol = red[col];
  __syncthreads();

  float sum = 0.f;
  for (int i = s + sub; i < e; i += 16)
    sum += expf(scores[(size_t)i * 16 + col] - mcol);
  red[t] = sum;
  __syncthreads();
  for (int step = 8; step >= 1; step >>= 1) {
    if (sub < step) red[t] += red[t + step * 16];
    __syncthreads();
  }
  if (t < 16) seg_sum[g * 16 + t] = red[t];
}

// ---------------------------------------------------------------------------
// K4: fused att + att.v + output GEMM (+bo).  out_attn built directly as the
//     MFMA A-tile in LDS (never touches HBM).  Also writes att.mean(axis=h).
// ---------------------------------------------------------------------------
__global__ __launch_bounds__(256) void out_kernel(
    const unsigned short* __restrict__ v_bf, const float* __restrict__ scores,
    const int* __restrict__ batch, const float* __restrict__ seg_max,
    const float* __restrict__ seg_sum, const unsigned short* __restrict__ Wo_t,
    const float* __restrict__ bo, float* __restrict__ out,
    float* __restrict__ att_mean) {
  __shared__ unsigned short Atile[BM][CC + 8];
  __shared__ unsigned short Btile[64][CC + 8];

  const int t = threadIdx.x;
  const int lane = t & 63;
  const int wave = t >> 6;
  const int lr = lane & 15;
  const int hi = lane >> 4;
  const int r0 = blockIdx.x * BM;

  // build A tile (out_attn, bf16): thread -> (node r, 16-wide d block)
  {
    int r = t >> 2;
    int dblk = t & 3;
    int gr = r0 + r;
    int b = batch[gr];
    const float* sc = scores + (size_t)gr * 16;
    const float* mx = seg_max + b * 16;
    const float* sm = seg_sum + b * 16;
    float att[16];
#pragma unroll
    for (int c2 = 0; c2 < 16; ++c2)
      att[c2] = expf(sc[c2] - mx[c2]) / (sm[c2] + 1e-16f);
    if (dblk == 0) {
#pragma unroll
      for (int g = 0; g < 4; ++g)
        att_mean[(size_t)gr * 4 + g] =
            0.25f * (att[g] + att[4 + g] + att[8 + g] + att[12 + g]);
    }
    float vv[4][16];
#pragma unroll
    for (int g = 0; g < 4; ++g) {
      const uint4* vp = reinterpret_cast<const uint4*>(
          v_bf + (size_t)gr * CC + g * 64 + dblk * 16);
      uint4 a = vp[0], b2 = vp[1];
      unsigned ua[8] = {a.x, a.y, a.z, a.w, b2.x, b2.y, b2.z, b2.w};
#pragma unroll
      for (int j = 0; j < 8; ++j) {
        vv[g][2 * j] = bflo(ua[j]);
        vv[g][2 * j + 1] = bfhi(ua[j]);
      }
    }
#pragma unroll
    for (int h = 0; h < 4; ++h) {
      unsigned short ob[16];
#pragma unroll
      for (int j = 0; j < 16; ++j) {
        float o = att[h * 4 + 0] * vv[0][j] + att[h * 4 + 1] * vv[1][j] +
                  att[h * 4 + 2] * vv[2][j] + att[h * 4 + 3] * vv[3][j];
        ob[j] = f2bf(o);
      }
      *reinterpret_cast<uint4*>(&Atile[r][h * 64 + dblk * 16]) =
          *reinterpret_cast<const uint4*>(&ob[0]);
      *reinterpret_cast<uint4*>(&Atile[r][h * 64 + dblk * 16 + 8]) =
          *reinterpret_cast<const uint4*>(&ob[8]);
    }
  }

  for (int c = 0; c < 4; ++c) {
    __syncthreads();
#pragma unroll
    for (int u = 0; u < 8; ++u) {
      int unit = t + u * 256;
      int row = unit >> 5, s8 = unit & 31;
      const uint4 w = *reinterpret_cast<const uint4*>(Wo_t + (size_t)(c * 64 + row) * 256 + s8 * 8);
      *reinterpret_cast<uint4*>(&Btile[row][s8 * 8]) = w;
    }
    __syncthreads();

    f32x4 acc[4];
#pragma unroll
    for (int m = 0; m < 4; ++m) acc[m] = (f32x4){0.f, 0.f, 0.f, 0.f};
#pragma unroll
    for (int ks = 0; ks < 8; ++ks) {
      bf16x8 bfrag = *reinterpret_cast<const bf16x8*>(&Btile[wave * 16 + lr][ks * 32 + hi * 8]);
#pragma unroll
      for (int m = 0; m < 4; ++m) {
        bf16x8 afrag = *reinterpret_cast<const bf16x8*>(&Atile[m * 16 + lr][ks * 32 + hi * 8]);
        acc[m] = __builtin_amdgcn_mfma_f32_16x16x32_bf16(afrag, bfrag, acc[m], 0, 0, 0);
      }
    }
    int colL = c * 64 + wave * 16 + lr;
    float bias = bo[colL];
#pragma unroll
    for (int m = 0; m < 4; ++m)
#pragma unroll
      for (int r = 0; r < 4; ++r) {
        int row = m * 16 + hi * 4 + r;
        out[(size_t)(r0 + row) * CC + colL] = acc[m][r] + bias;
      }
  }
}

// ---------------------------------------------------------------------------
extern "C" void kernel_launch(void* const* d_in, const int* in_sizes, int n_in,
                              void* d_out, int out_size, void* d_ws, size_t ws_size,
                              hipStream_t stream) {
  const float* x  = (const float*)d_in[0];
  const int* batch = (const int*)d_in[1];
  const float* Wq = (const float*)d_in[2];
  const float* bq = (const float*)d_in[3];
  const float* Wk = (const float*)d_in[4];
  const float* bk = (const float*)d_in[5];
  const float* Wv = (const float*)d_in[6];
  const float* bv = (const float*)d_in[7];
  const float* Wo = (const float*)d_in[8];
  const float* bo = (const float*)d_in[9];

  char* ws = (char*)d_ws;
  unsigned short* Wqkv_t = (unsigned short*)ws;              //   393,216 B
  unsigned short* Wo_t   = (unsigned short*)(ws + 393216);   //   131,072 B
  int*   seg_start = (int*)(ws + 524288);                    //     2,052 B (pad to 4096)
  float* seg_max   = (float*)(ws + 528384);                  //    32,768 B
  float* seg_sum   = (float*)(ws + 561152);                  //    32,768 B
  float* scores    = (float*)(ws + 593920);                  // 12,800,000 B
  unsigned short* v_bf = (unsigned short*)(ws + 13393920);   // 102,400,000 B
  // total ws use: 115,793,920 B

  float* out = (float*)d_out;
  float* att_mean = out + (size_t)NN * CC;

  prep_kernel<<<1024, 256, 0, stream>>>(Wq, Wk, Wv, Wo, Wqkv_t, Wo_t);
  seg_bounds_kernel<<<(NN + 255) / 256, 256, 0, stream>>>(batch, seg_start, NN);
  qkv_scores_kernel<<<NN / BM, 256, 0, stream>>>(x, Wqkv_t, bq, bk, bv, v_bf, scores);
  seg_softmax_kernel<<<NG, 256, 0, stream>>>(scores, seg_start, seg_max, seg_sum);
  out_kernel<<<NN / BM, 256, 0, stream>>>(v_bf, scores, batch, seg_max, seg_sum,
                                          Wo_t, bo, out, att_mean);
}

// Round 2
// 334.285 us; speedup vs baseline: 1.2949x; 1.2949x over previous
//
#include <hip/hip_runtime.h>

// Problem constants (fixed by the reference)
#define NN 200000   // nodes
#define CC 256      // channels
#define NG 512      // graphs/segments
#define BM 64       // node rows per block (200000 = 3125 * 64 exactly)

typedef __attribute__((ext_vector_type(8))) __bf16 bf16x8;
typedef __attribute__((ext_vector_type(4))) float f32x4;

__device__ __forceinline__ unsigned short f2bf(float f) {
  union { float f; unsigned u; } v; v.f = f;
  unsigned u = v.u;
  u += 0x7fffu + ((u >> 16) & 1u);   // RNE
  return (unsigned short)(u >> 16);
}
__device__ __forceinline__ float bflo(unsigned u){ union{unsigned u; float f;} x; x.u = u << 16; return x.f; }
__device__ __forceinline__ float bfhi(unsigned u){ union{unsigned u; float f;} x; x.u = u & 0xffff0000u; return x.f; }

// ---------------------------------------------------------------------------
// K0: prep.
//  Wfrag: QKV weights in MFMA B-fragment order, chunk order V(0..3),Q(4..7),K(8..11).
//   index = ((c*4 + wc)*8 + ks)*512 + lane*8 + j
//   holds W^T[col = c*64 + wc*16 + (lane&15)][k = ks*32 + (lane>>4)*8 + j]
//  Wo_t: plain transpose [col][k] (out_kernel unchanged).
// ---------------------------------------------------------------------------
__global__ __launch_bounds__(256) void prep_kernel(
    const float* __restrict__ Wq, const float* __restrict__ Wk,
    const float* __restrict__ Wv, const float* __restrict__ Wo,
    unsigned short* __restrict__ Wfrag, unsigned short* __restrict__ Wo_t) {
  int idx = blockIdx.x * 256 + threadIdx.x;
  if (idx < 196608) {
    int c   = idx >> 14;
    int r1  = idx & 16383;
    int wc  = r1 >> 12;
    int r2  = r1 & 4095;
    int ks  = r2 >> 9;
    int r3  = r2 & 511;
    int lane = r3 >> 3;
    int j   = r3 & 7;
    int lr = lane & 15, hi = lane >> 4;
    int col = wc * 16 + lr;              // 0..63 within chunk
    int k = ks * 32 + hi * 8 + j;        // 0..255
    float w;
    if (c < 4)      w = Wv[k * 256 + (c * 64 + col)];
    else if (c < 8) w = Wq[k * 256 + ((c - 4) * 64 + col)];
    else            w = Wk[k * 256 + ((c - 8) * 64 + col)];
    Wfrag[idx] = f2bf(w);
  } else {
    int j = idx - 196608;                // 0..65535
    int c = j >> 8, k = j & 255;
    Wo_t[j] = f2bf(Wo[k * 256 + c]);
  }
}

// ---------------------------------------------------------------------------
// K1: segment boundaries from sorted batch.
// ---------------------------------------------------------------------------
__global__ __launch_bounds__(256) void seg_bounds_kernel(
    const int* __restrict__ batch, int* __restrict__ seg_start, int n) {
  int i = blockIdx.x * 256 + threadIdx.x;
  if (i >= n) return;
  int a = batch[i];
  int b = (i + 1 < n) ? batch[i + 1] : NG;
  for (int g = a + 1; g <= b; ++g) seg_start[g] = i + 1;
  if (i == 0) for (int g = 0; g <= a; ++g) seg_start[g] = 0;
}

// ---------------------------------------------------------------------------
// K2: fused QKV GEMM + per-node scores.  1024 threads = 16 waves (4x4 grid).
//  Chunk order: V(0..3) -> Vst union region -> global;  Q(4..7),K(8..11) -> QK LDS.
//  A: x staged once, bf16, XOR-swizzled frag layout (conflict-free ds_read_b128).
//  B: global_load_lds dwordx4 from frag-ordered Wfrag, next chunk prefetched
//     after frag reads (latency hidden under MFMA + epilogue).
//  LDS: At 32768 + Bt 32768 + U 66560 = 132,096 B -> 1 block/CU, 16 waves.
// ---------------------------------------------------------------------------
__device__ __forceinline__ void issue_b_loads(
    const unsigned short* __restrict__ Wfrag, unsigned short* Bt,
    int c, int w, int lane) {
#pragma unroll
  for (int rep = 0; rep < 2; ++rep) {
    int unit = (w * 2 + rep) * 64 + lane;
    const unsigned short* src = Wfrag + c * 16384 + unit * 8;
    unsigned short* dst = &Bt[(w * 2 + rep) * 64 * 8];  // wave-uniform base
    __builtin_amdgcn_global_load_lds(
        (const __attribute__((address_space(1))) void*)src,
        (__attribute__((address_space(3))) void*)dst, 16, 0, 0);
  }
}

__global__ __launch_bounds__(1024, 4) void qkv_scores_kernel(
    const float* __restrict__ x, const unsigned short* __restrict__ Wfrag,
    const float* __restrict__ bq, const float* __restrict__ bk,
    const float* __restrict__ bv,
    unsigned short* __restrict__ v_out,   // [NN][256] bf16
    float* __restrict__ scores) {         // [NN][16]
  __shared__ unsigned short At[16384];    // ((wr*8+ks)*64 + (lane^ks))*8 + j
  __shared__ unsigned short Bt[16384];    // ((wc*8+ks)*64 + lane)*8 + j
  __shared__ unsigned short U[64 * 520];  // QK[row][0..511] stride 520; Vst union

  const int t = threadIdx.x;
  const int lane = t & 63;
  const int w = t >> 6;                 // 0..15
  const int wr = w >> 2, wc = w & 3;
  const int lr = lane & 15, hi = lane >> 4;
  const int r0 = blockIdx.x * BM;

  // ---- stage A: x fp32 -> bf16 frag layout (coalesced float4 reads) ----
#pragma unroll
  for (int it = 0; it < 4; ++it) {
    int u = it * 1024 + t;
    int row = u >> 6, c4 = u & 63;
    const float4 v = *reinterpret_cast<const float4*>(
        x + (size_t)(r0 + row) * CC + c4 * 4);
    int k = c4 * 4;
    int ks = k >> 5, ahi = (k >> 3) & 3, j0 = k & 7;
    int al = (ahi * 16 + (row & 15)) ^ ks;
    uint2 pk;
    pk.x = (unsigned)f2bf(v.x) | ((unsigned)f2bf(v.y) << 16);
    pk.y = (unsigned)f2bf(v.z) | ((unsigned)f2bf(v.w) << 16);
    *reinterpret_cast<uint2*>(&At[(((row >> 4) * 8 + ks) * 64 + al) * 8 + j0]) = pk;
  }

  issue_b_loads(Wfrag, Bt, 0, w, lane);

  for (int c = 0; c < 12; ++c) {
    asm volatile("s_waitcnt vmcnt(0)" ::: "memory");
    __syncthreads();   // Bt[c] visible; A staged; prev epilogue done
    bf16x8 bfr[8];
#pragma unroll
    for (int ks = 0; ks < 8; ++ks)
      bfr[ks] = *reinterpret_cast<const bf16x8*>(&Bt[(wc * 8 + ks) * 512 + lane * 8]);
    __syncthreads();   // all waves done reading Bt (barrier drains lgkm)
    if (c + 1 < 12) issue_b_loads(Wfrag, Bt, c + 1, w, lane);

    f32x4 acc = {0.f, 0.f, 0.f, 0.f};
#pragma unroll
    for (int ks = 0; ks < 8; ++ks) {
      bf16x8 afr = *reinterpret_cast<const bf16x8*>(
          &At[((wr * 8 + ks) * 64 + (lane ^ ks)) * 8]);
      acc = __builtin_amdgcn_mfma_f32_16x16x32_bf16(afr, bfr[ks], acc, 0, 0, 0);
    }

    if (c < 4) {              // V head c -> Vst (union region) -> global bf16
      int colc = wc * 16 + lr;
      float bias = bv[c * 64 + colc];
#pragma unroll
      for (int r = 0; r < 4; ++r)
        U[(wr * 16 + hi * 4 + r) * 520 + colc] = f2bf(acc[r] + bias);
      __syncthreads();
      {
        int row = t >> 4, q8 = t & 15;
        uint2 d = *reinterpret_cast<const uint2*>(&U[row * 520 + q8 * 4]);
        *reinterpret_cast<uint2*>(
            v_out + (size_t)(r0 + row) * CC + c * 64 + q8 * 4) = d;
      }
    } else if (c < 8) {       // Q
      int col = (c - 4) * 64 + wc * 16 + lr;
      float bias = bq[col];
#pragma unroll
      for (int r = 0; r < 4; ++r)
        U[(wr * 16 + hi * 4 + r) * 520 + col] = f2bf(acc[r] + bias);
    } else {                  // K
      int col = (c - 8) * 64 + wc * 16 + lr;
      float bias = bk[col];
#pragma unroll
      for (int r = 0; r < 4; ++r)
        U[(wr * 16 + hi * 4 + r) * 520 + 256 + col] = f2bf(acc[r] + bias);
    }
  }

  __syncthreads();
  // ---- scores epilogue: 1024 threads = 64 nodes x 16 (h,g) ----
  {
    int node = t >> 4, col = t & 15;
    int h = col >> 2, g = col & 3;
    const unsigned short* qrow = &U[node * 520 + h * 64];
    const unsigned short* krow = &U[node * 520 + 256 + g * 64];
    float s = 0.f;
#pragma unroll
    for (int d0 = 0; d0 < 64; d0 += 8) {
      uint4 qv = *reinterpret_cast<const uint4*>(qrow + d0);
      uint4 kv = *reinterpret_cast<const uint4*>(krow + d0);
      s += bflo(qv.x) * bflo(kv.x) + bfhi(qv.x) * bfhi(kv.x);
      s += bflo(qv.y) * bflo(kv.y) + bfhi(qv.y) * bfhi(kv.y);
      s += bflo(qv.z) * bflo(kv.z) + bfhi(qv.z) * bfhi(kv.z);
      s += bflo(qv.w) * bflo(kv.w) + bfhi(qv.w) * bfhi(kv.w);
    }
    scores[(size_t)(r0 + node) * 16 + col] = s * 0.125f;
  }
}

// ---------------------------------------------------------------------------
// K3: per-segment max & exp-sum over the 16 score columns (block per segment).
// ---------------------------------------------------------------------------
__global__ __launch_bounds__(256) void seg_softmax_kernel(
    const float* __restrict__ scores, const int* __restrict__ seg_start,
    float* __restrict__ seg_max, float* __restrict__ seg_sum) {
  __shared__ float red[256];
  int g = blockIdx.x;
  int s = seg_start[g], e = seg_start[g + 1];
  int t = threadIdx.x;
  int col = t & 15, sub = t >> 4;

  float m = -INFINITY;
  for (int i = s + sub; i < e; i += 16)
    m = fmaxf(m, scores[(size_t)i * 16 + col]);
  red[t] = m;
  __syncthreads();
  for (int step = 8; step >= 1; step >>= 1) {
    if (sub < step) red[t] = fmaxf(red[t], red[t + step * 16]);
    __syncthreads();
  }
  if (t < 16) seg_max[g * 16 + t] = red[t];
  float mcol = red[col];
  __syncthreads();

  float sum = 0.f;
  for (int i = s + sub; i < e; i += 16)
    sum += expf(scores[(size_t)i * 16 + col] - mcol);
  red[t] = sum;
  __syncthreads();
  for (int step = 8; step >= 1; step >>= 1) {
    if (sub < step) red[t] += red[t + step * 16];
    __syncthreads();
  }
  if (t < 16) seg_sum[g * 16 + t] = red[t];
}

// ---------------------------------------------------------------------------
// K4: fused att + att.v + output GEMM (+bo).  (unchanged this round)
// ---------------------------------------------------------------------------
__global__ __launch_bounds__(256) void out_kernel(
    const unsigned short* __restrict__ v_bf, const float* __restrict__ scores,
    const int* __restrict__ batch, const float* __restrict__ seg_max,
    const float* __restrict__ seg_sum, const unsigned short* __restrict__ Wo_t,
    const float* __restrict__ bo, float* __restrict__ out,
    float* __restrict__ att_mean) {
  __shared__ unsigned short Atile[BM][CC + 8];
  __shared__ unsigned short Btile[64][CC + 8];

  const int t = threadIdx.x;
  const int lane = t & 63;
  const int wave = t >> 6;
  const int lr = lane & 15;
  const int hi = lane >> 4;
  const int r0 = blockIdx.x * BM;

  // build A tile (out_attn, bf16): thread -> (node r, 16-wide d block)
  {
    int r = t >> 2;
    int dblk = t & 3;
    int gr = r0 + r;
    int b = batch[gr];
    const float* sc = scores + (size_t)gr * 16;
    const float* mx = seg_max + b * 16;
    const float* sm = seg_sum + b * 16;
    float att[16];
#pragma unroll
    for (int c2 = 0; c2 < 16; ++c2)
      att[c2] = expf(sc[c2] - mx[c2]) / (sm[c2] + 1e-16f);
    if (dblk == 0) {
#pragma unroll
      for (int g = 0; g < 4; ++g)
        att_mean[(size_t)gr * 4 + g] =
            0.25f * (att[g] + att[4 + g] + att[8 + g] + att[12 + g]);
    }
    float vv[4][16];
#pragma unroll
    for (int g = 0; g < 4; ++g) {
      const uint4* vp = reinterpret_cast<const uint4*>(
          v_bf + (size_t)gr * CC + g * 64 + dblk * 16);
      uint4 a = vp[0], b2 = vp[1];
      unsigned ua[8] = {a.x, a.y, a.z, a.w, b2.x, b2.y, b2.z, b2.w};
#pragma unroll
      for (int j = 0; j < 8; ++j) {
        vv[g][2 * j] = bflo(ua[j]);
        vv[g][2 * j + 1] = bfhi(ua[j]);
      }
    }
#pragma unroll
    for (int h = 0; h < 4; ++h) {
      unsigned short ob[16];
#pragma unroll
      for (int j = 0; j < 16; ++j) {
        float o = att[h * 4 + 0] * vv[0][j] + att[h * 4 + 1] * vv[1][j] +
                  att[h * 4 + 2] * vv[2][j] + att[h * 4 + 3] * vv[3][j];
        ob[j] = f2bf(o);
      }
      *reinterpret_cast<uint4*>(&Atile[r][h * 64 + dblk * 16]) =
          *reinterpret_cast<const uint4*>(&ob[0]);
      *reinterpret_cast<uint4*>(&Atile[r][h * 64 + dblk * 16 + 8]) =
          *reinterpret_cast<const uint4*>(&ob[8]);
    }
  }

  for (int c = 0; c < 4; ++c) {
    __syncthreads();
#pragma unroll
    for (int u = 0; u < 8; ++u) {
      int unit = t + u * 256;
      int row = unit >> 5, s8 = unit & 31;
      const uint4 wv = *reinterpret_cast<const uint4*>(
          Wo_t + (size_t)(c * 64 + row) * 256 + s8 * 8);
      *reinterpret_cast<uint4*>(&Btile[row][s8 * 8]) = wv;
    }
    __syncthreads();

    f32x4 acc[4];
#pragma unroll
    for (int m = 0; m < 4; ++m) acc[m] = (f32x4){0.f, 0.f, 0.f, 0.f};
#pragma unroll
    for (int ks = 0; ks < 8; ++ks) {
      bf16x8 bfrag = *reinterpret_cast<const bf16x8*>(&Btile[wave * 16 + lr][ks * 32 + hi * 8]);
#pragma unroll
      for (int m = 0; m < 4; ++m) {
        bf16x8 afrag = *reinterpret_cast<const bf16x8*>(&Atile[m * 16 + lr][ks * 32 + hi * 8]);
        acc[m] = __builtin_amdgcn_mfma_f32_16x16x32_bf16(afrag, bfrag, acc[m], 0, 0, 0);
      }
    }
    int colL = c * 64 + wave * 16 + lr;
    float bias = bo[colL];
#pragma unroll
    for (int m = 0; m < 4; ++m)
#pragma unroll
      for (int r = 0; r < 4; ++r) {
        int row = m * 16 + hi * 4 + r;
        out[(size_t)(r0 + row) * CC + colL] = acc[m][r] + bias;
      }
  }
}

// ---------------------------------------------------------------------------
extern "C" void kernel_launch(void* const* d_in, const int* in_sizes, int n_in,
                              void* d_out, int out_size, void* d_ws, size_t ws_size,
                              hipStream_t stream) {
  const float* x  = (const float*)d_in[0];
  const int* batch = (const int*)d_in[1];
  const float* Wq = (const float*)d_in[2];
  const float* bq = (const float*)d_in[3];
  const float* Wk = (const float*)d_in[4];
  const float* bk = (const float*)d_in[5];
  const float* Wv = (const float*)d_in[6];
  const float* bv = (const float*)d_in[7];
  const float* Wo = (const float*)d_in[8];
  const float* bo = (const float*)d_in[9];

  char* ws = (char*)d_ws;
  unsigned short* Wfrag = (unsigned short*)ws;               //   393,216 B
  unsigned short* Wo_t  = (unsigned short*)(ws + 393216);    //   131,072 B
  int*   seg_start = (int*)(ws + 524288);                    //     2,052 B (pad to 4096)
  float* seg_max   = (float*)(ws + 528384);                  //    32,768 B
  float* seg_sum   = (float*)(ws + 561152);                  //    32,768 B
  float* scores    = (float*)(ws + 593920);                  // 12,800,000 B
  unsigned short* v_bf = (unsigned short*)(ws + 13393920);   // 102,400,000 B

  float* out = (float*)d_out;
  float* att_mean = out + (size_t)NN * CC;

  prep_kernel<<<1024, 256, 0, stream>>>(Wq, Wk, Wv, Wo, Wfrag, Wo_t);
  seg_bounds_kernel<<<(NN + 255) / 256, 256, 0, stream>>>(batch, seg_start, NN);
  qkv_scores_kernel<<<NN / BM, 1024, 0, stream>>>(x, Wfrag, bq, bk, bv, v_bf, scores);
  seg_softmax_kernel<<<NG, 256, 0, stream>>>(scores, seg_start, seg_max, seg_sum);
  out_kernel<<<NN / BM, 256, 0, stream>>>(v_bf, scores, batch, seg_max, seg_sum,
                                          Wo_t, bo, out, att_mean);
}